// Round 5
// baseline (147.335 us; speedup 1.0000x reference)
//
#include <hip/hip_runtime.h>
#include <math.h>

#define BB 8
#define TT 16384
#define DD 128
#define DH 64
#define FCAP 32768
#define FMARGIN 0.02f

typedef short short8 __attribute__((ext_vector_type(8)));
typedef float f32x4  __attribute__((ext_vector_type(4)));

static __device__ __forceinline__ float4 ld4(const float* p) { return *(const float4*)p; }

// bf16 round-to-nearest-even
static __device__ __forceinline__ uint f2bf(float x) {
    uint u = __float_as_uint(x);
    return (u + 0x7FFFu + ((u >> 16) & 1u)) >> 16;
}
// pack value x ~= hi + lo (both bf16) into u32 = (hi<<16)|lo
static __device__ __forceinline__ uint packhl(float x) {
    uint hb = f2bf(x);
    float hf = __uint_as_float(hb << 16);
    uint lb = f2bf(x - hf);
    return (hb << 16) | lb;
}

// split 8 fp32 -> hi bf16x8 + lo bf16x8 (in-register, no LDS round-trip)
static __device__ __forceinline__ void split8(const float4 v0, const float4 v1,
                                              short8* ah, short8* al)
{
    float f[8] = {v0.x, v0.y, v0.z, v0.w, v1.x, v1.y, v1.z, v1.w};
    union { uint u[4]; short8 s; } H, L;
    #pragma unroll
    for (int j = 0; j < 4; ++j) {
        uint h0 = f2bf(f[2 * j]);
        uint h1 = f2bf(f[2 * j + 1]);
        uint l0 = f2bf(f[2 * j]     - __uint_as_float(h0 << 16));
        uint l1 = f2bf(f[2 * j + 1] - __uint_as_float(h1 << 16));
        H.u[j] = h0 | (h1 << 16);
        L.u[j] = l0 | (l1 << 16);
    }
    *ah = H.s; *al = L.s;
}

// ---------------------------------------------------------------------------
// Kernel W-prep: weights fp32 -> bf16 MFMA B-fragment layout.
// ly 0..2: MLP layers Wa1/Wa2/Wd -> wfm (hi only; MLP tolerates bf16 W).
// ly 3: bind [Wk|Wq] -> wfb hi frags [0, D*D) and lo frags [D*D, 2*D*D).
// Frag (nt, kb): lane l, elem e holds W[kb*32 + (l>>4)*8 + e][nt*16 + (l&15)].
// Also zeroes the fixup counter (runs before k_bind).
// ---------------------------------------------------------------------------
__global__ __launch_bounds__(64) void k_wprep(
    const float* __restrict__ Wa1, const float* __restrict__ Wa2,
    const float* __restrict__ Wd, const float* __restrict__ Wk,
    const float* __restrict__ Wq, ushort* __restrict__ wfm,
    ushort* __restrict__ wfb, int* __restrict__ fcnt)
{
    const int l  = threadIdx.x;
    const int nt = blockIdx.x & 7;
    const int kb = blockIdx.x >> 3;
    const int ly = blockIdx.y;
    if (ly == 0 && blockIdx.x == 0 && l == 0) *fcnt = 0;
    const int n  = nt * 16 + (l & 15);
    const int k0 = kb * 32 + (l >> 4) * 8;
    if (ly < 3) {
        const float* W = (ly == 0) ? Wa1 : (ly == 1) ? Wa2 : Wd;
        short8 v;
        #pragma unroll
        for (int e = 0; e < 8; ++e) v[e] = (short)(ushort)f2bf(W[(k0 + e) * DD + n]);
        *(short8*)(wfm + (size_t)(((ly * 8 + nt) * 4 + kb) * 64 + l) * 8) = v;
    } else {
        short8 vh, vl;
        #pragma unroll
        for (int e = 0; e < 8; ++e) {
            float w = (n < 64) ? Wk[(k0 + e) * DH + n] : Wq[(k0 + e) * DH + n - 64];
            uint hb = f2bf(w);
            vh[e] = (short)(ushort)hb;
            vl[e] = (short)(ushort)f2bf(w - __uint_as_float(hb << 16));
        }
        *(short8*)(wfb + (size_t)((nt * 4 + kb) * 64 + l) * 8) = vh;
        *(short8*)(wfb + (size_t)DD * DD + (size_t)((nt * 4 + kb) * 64 + l) * 8) = vl;
    }
}

// ---------------------------------------------------------------------------
// Kernel 1: binding logits via MFMA, 3-product split (ah*wh + al*wh + ah*wl).
// A-frags loaded DIRECTLY from global x (no LDS staging): lane needs row
// tb+wv*16+lo16, elems kb*32+g*8..+7 = two float4 loads (lanes g=0..3 of a
// row form one contiguous 128B segment -> coalesced). LDS holds only the
// post-MFMA K/Q tile (34 KB -> 4 blocks/CU); single barrier.
// Tile 4 (Q row 64): rows 1..15 use zero A-frags; only 4 lanes load row 64.
// Biases folded into fp32 accumulator init. |dot|<FMARGIN -> fixup list.
// ---------------------------------------------------------------------------
__global__ __launch_bounds__(256) void k_bind(
    const float* __restrict__ x, const ushort* __restrict__ wfb,
    const float* __restrict__ bk, const float* __restrict__ bq,
    int* __restrict__ cstart, int* __restrict__ flist, int* __restrict__ fcnt)
{
    __shared__ struct { float K[64][66]; float Q[65][66]; } kq;   // 34.1 KB
    const int b    = blockIdx.y;
    const int tb   = blockIdx.x * 64;
    const int tid  = threadIdx.x;
    const int wv   = tid >> 6;
    const int l    = tid & 63;
    const int lo16 = l & 15;
    const int g    = l >> 4;

    // main m-tile: rows wv*16..+15, n-tiles 0..7 (K cols 0..63 | Q cols 64..127)
    f32x4 acc[8];
    #pragma unroll
    for (int nt = 0; nt < 8; ++nt) {
        int col = nt * 16 + lo16;
        float bias = (col < 64) ? bk[col] : bq[col - 64];
        acc[nt] = (f32x4){bias, bias, bias, bias};
    }
    const float* xrow = x + ((size_t)b * TT + tb + wv * 16 + lo16) * DD;
    #pragma unroll
    for (int kb = 0; kb < 4; ++kb) {
        float4 v0 = ld4(xrow + kb * 32 + g * 8);
        float4 v1 = ld4(xrow + kb * 32 + g * 8 + 4);
        short8 ah, al;
        split8(v0, v1, &ah, &al);
        #pragma unroll
        for (int nt = 0; nt < 8; ++nt) {
            short8 bh = *(const short8*)(wfb + (size_t)((nt * 4 + kb) * 64 + l) * 8);
            short8 bl = *(const short8*)(wfb + (size_t)DD * DD + (size_t)((nt * 4 + kb) * 64 + l) * 8);
            acc[nt] = __builtin_amdgcn_mfma_f32_16x16x32_bf16(ah, bh, acc[nt], 0, 0, 0);
            acc[nt] = __builtin_amdgcn_mfma_f32_16x16x32_bf16(al, bh, acc[nt], 0, 0, 0);
            acc[nt] = __builtin_amdgcn_mfma_f32_16x16x32_bf16(ah, bl, acc[nt], 0, 0, 0);
        }
    }

    // tile 4: Q row 64 only (A rows 1..15 zero). n-tile = 4+wv.
    f32x4 acc4;
    {
        int col = (4 + wv) * 16 + lo16;
        float bias = bq[col - 64];
        acc4 = (f32x4){bias, bias, bias, bias};
    }
    {
        int r64 = tb + 64; if (r64 > TT - 1) r64 = TT - 1;   // clamp (value unused when t>TT-2)
        const float* xq = x + ((size_t)b * TT + r64) * DD;
        #pragma unroll
        for (int kb = 0; kb < 4; ++kb) {
            short8 ah = (short8)0, al = (short8)0;
            if (lo16 == 0) {
                float4 v0 = ld4(xq + kb * 32 + g * 8);
                float4 v1 = ld4(xq + kb * 32 + g * 8 + 4);
                split8(v0, v1, &ah, &al);
            }
            short8 bh = *(const short8*)(wfb + (size_t)(((4 + wv) * 4 + kb) * 64 + l) * 8);
            short8 bl = *(const short8*)(wfb + (size_t)DD * DD + (size_t)(((4 + wv) * 4 + kb) * 64 + l) * 8);
            acc4 = __builtin_amdgcn_mfma_f32_16x16x32_bf16(ah, bh, acc4, 0, 0, 0);
            acc4 = __builtin_amdgcn_mfma_f32_16x16x32_bf16(al, bh, acc4, 0, 0, 0);
            acc4 = __builtin_amdgcn_mfma_f32_16x16x32_bf16(ah, bl, acc4, 0, 0, 0);
        }
    }

    // C/D layout: col = lane&15 (+nt*16), row = (lane>>4)*4 + reg
    #pragma unroll
    for (int nt = 0; nt < 8; ++nt)
        #pragma unroll
        for (int i = 0; i < 4; ++i) {
            int row = wv * 16 + g * 4 + i;
            int col = nt * 16 + lo16;
            if (nt < 4) kq.K[row][col]      = acc[nt][i];
            else        kq.Q[row][col - 64] = acc[nt][i];
        }
    if (g == 0) kq.Q[64][wv * 16 + lo16] = acc4[0];   // row 64 = reg 0 of g==0
    __syncthreads();

    // dot: 4 threads per bind index, 16 elems each
    const int tr = tid >> 2, part = tid & 3;
    float s = 0.f;
    #pragma unroll
    for (int j4 = 0; j4 < 4; ++j4) {
        float4 kv = *(const float4*)&kq.K[tr][part * 16 + j4 * 4];
        float4 qv = *(const float4*)&kq.Q[tr + 1][part * 16 + j4 * 4];
        s += kv.x * qv.x + kv.y * qv.y + kv.z * qv.z + kv.w * qv.w;
    }
    s += __shfl_xor(s, 1);
    s += __shfl_xor(s, 2);
    if (part == 0) {
        int t = tb + tr;
        if (t <= TT - 2) {
            cstart[b * TT + t + 1] = (s > 0.f) ? 0 : 1;
            if (fabsf(s) < FMARGIN) {
                int pos = atomicAdd(fcnt, 1);
                if (pos < FCAP) flist[pos] = b * TT + t;
            }
        }
    }
    if (blockIdx.x == 0 && tid == 0) cstart[b * TT] = 1;
}

// ---------------------------------------------------------------------------
// Kernel 1b: exact fp32 recompute of flagged borderline bind decisions.
// One wave per flagged entry, grid-strided; ~300 entries expected.
// ---------------------------------------------------------------------------
__global__ __launch_bounds__(256) void k_fixup(
    const float* __restrict__ x, const float* __restrict__ Wk, const float* __restrict__ bk,
    const float* __restrict__ Wq, const float* __restrict__ bq,
    const int* __restrict__ flist, const int* __restrict__ fcnt, int* __restrict__ cstart)
{
    const int n    = min(*fcnt, FCAP);
    const int wv   = (blockIdx.x * 256 + threadIdx.x) >> 6;
    const int lane = threadIdx.x & 63;
    const int nwv  = gridDim.x * 4;
    for (int i = wv; i < n; i += nwv) {
        int idx = flist[i];
        int b = idx >> 14;           // / TT
        int t = idx & (TT - 1);
        const float* xt = x + ((size_t)b * TT + t) * DD;
        float K = bk[lane], Q = bq[lane];
        #pragma unroll 8
        for (int k = 0; k < DD; ++k) {
            K = fmaf(xt[k],      Wk[k * DH + lane], K);
            Q = fmaf(xt[DD + k], Wq[k * DH + lane], Q);
        }
        float p = K * Q;
        #pragma unroll
        for (int m = 1; m < 64; m <<= 1) p += __shfl_xor(p, m);
        if (lane == 0) cstart[b * TT + t + 1] = (p > 0.f) ? 0 : 1;
    }
}

// ---------------------------------------------------------------------------
// Kernel 2: per-batch scan -> seg, chunk-start table, counts. (unchanged)
// ---------------------------------------------------------------------------
__global__ __launch_bounds__(1024) void k_scan(const int* __restrict__ cstart,
    int* __restrict__ seg, int* __restrict__ cs, int* __restrict__ numC)
{
    __shared__ int lds[1024];
    const int b = blockIdx.x, tid = threadIdx.x;
    const int base = b * TT + tid * 16;
    int v[16];
    #pragma unroll
    for (int i = 0; i < 4; ++i) {
        int4 q = *(const int4*)(cstart + base + i * 4);
        v[i * 4 + 0] = q.x; v[i * 4 + 1] = q.y; v[i * 4 + 2] = q.z; v[i * 4 + 3] = q.w;
    }
    int s[16]; int run = 0;
    #pragma unroll
    for (int i = 0; i < 16; ++i) { run += v[i]; s[i] = run; }
    lds[tid] = run;
    __syncthreads();
    for (int off = 1; off < 1024; off <<= 1) {
        int t = (tid >= off) ? lds[tid - off] : 0;
        __syncthreads();
        lds[tid] += t;
        __syncthreads();
    }
    const int excl = lds[tid] - run;
    #pragma unroll
    for (int i = 0; i < 16; ++i) {
        int sg = excl + s[i] - 1;
        seg[base + i] = sg;
        if (v[i]) cs[b * (TT + 1) + sg] = tid * 16 + i;
    }
    if (tid == 0) {
        int tot = lds[1023];
        numC[b] = tot;
        cs[b * (TT + 1) + tot] = TT;
    }
}

// ---------------------------------------------------------------------------
// Kernel 3a: chunk means. (unchanged)
// ---------------------------------------------------------------------------
__global__ __launch_bounds__(256) void k_mean(const float* __restrict__ x,
    const int* __restrict__ cs, const int* __restrict__ numC, float* __restrict__ cm)
{
    const int w    = blockIdx.x * 4 + (threadIdx.x >> 6);
    const int lane = threadIdx.x & 63;
    const int b    = w >> 14;
    const int c    = w & (TT - 1);
    if (c >= numC[b]) return;
    const int t0 = cs[b * (TT + 1) + c], t1 = cs[b * (TT + 1) + c + 1];
    float sx = 0.f, sy = 0.f;
    const float* xp = x + ((size_t)b * TT + t0) * DD + lane * 2;
    for (int t = t0; t < t1; ++t, xp += DD) { sx += xp[0]; sy += xp[1]; }
    const float inv = 1.f / (float)(t1 - t0);
    float* o = cm + ((size_t)b * TT + c) * DD + lane * 2;
    o[0] = sx * inv; o[1] = sy * inv;
}

// ---------------------------------------------------------------------------
// k_mlp GEMM helper: acc[8] (16x128 per wave) = A(split hi+lo) @ W_bf16.
// ---------------------------------------------------------------------------
__device__ __forceinline__ void mlp_gemm(f32x4 acc[8], const uint (*As)[132],
    const ushort* __restrict__ wl, int m, int g, int l)
{
    #pragma unroll
    for (int nt = 0; nt < 8; ++nt) acc[nt] = (f32x4){0.f, 0.f, 0.f, 0.f};
    #pragma unroll
    for (int kb = 0; kb < 4; ++kb) {
        short8 bh[8];
        #pragma unroll
        for (int nt = 0; nt < 8; ++nt)
            bh[nt] = *(const short8*)(wl + (size_t)((nt * 4 + kb) * 64 + l) * 8);
        uint4 p0 = *(const uint4*)&As[m][kb * 32 + g * 8];
        uint4 p1 = *(const uint4*)&As[m][kb * 32 + g * 8 + 4];
        uint pp[8] = {p0.x, p0.y, p0.z, p0.w, p1.x, p1.y, p1.z, p1.w};
        union { uint u[4]; short8 s; } ah, al;
        #pragma unroll
        for (int j = 0; j < 4; ++j) {
            ah.u[j] = (pp[2 * j] >> 16)      | (pp[2 * j + 1] & 0xFFFF0000u);
            al.u[j] = (pp[2 * j] & 0xFFFFu)  | (pp[2 * j + 1] << 16);
        }
        #pragma unroll
        for (int nt = 0; nt < 8; ++nt) {
            acc[nt] = __builtin_amdgcn_mfma_f32_16x16x32_bf16(ah.s, bh[nt], acc[nt], 0, 0, 0);
            acc[nt] = __builtin_amdgcn_mfma_f32_16x16x32_bf16(al.s, bh[nt], acc[nt], 0, 0, 0);
        }
    }
}

// ---------------------------------------------------------------------------
// Kernel 3b: per-chunk MLP via MFMA. (unchanged from round 2)
// ---------------------------------------------------------------------------
__global__ __launch_bounds__(256) void k_mlp(
    const float* __restrict__ ba1, const float* __restrict__ ln_g, const float* __restrict__ ln_b,
    const float* __restrict__ ba2, const float* __restrict__ bd,
    const ushort* __restrict__ wf, const int* __restrict__ numC, float* __restrict__ cm)
{
    __shared__ uint As[64][132];
    const int b  = blockIdx.y;
    const int nC = numC[b];
    const int c0 = blockIdx.x * 64;
    if (c0 >= nC) return;
    const int tid  = threadIdx.x;
    const int wv   = tid >> 6;
    const int l    = tid & 63;
    const int lo16 = l & 15;
    const int g    = l >> 4;
    const int m    = wv * 16 + lo16;

    for (int i = tid; i < 64 * 32; i += 256) {
        int r = i >> 5, c4 = (i & 31) * 4;
        float4 v = make_float4(0.f, 0.f, 0.f, 0.f);
        if (c0 + r < nC) v = ld4(cm + ((size_t)b * TT + c0 + r) * DD + c4);
        uint4 pk;
        pk.x = packhl(v.x); pk.y = packhl(v.y); pk.z = packhl(v.z); pk.w = packhl(v.w);
        *(uint4*)&As[r][c4] = pk;
    }
    __syncthreads();

    f32x4 acc[8];
    mlp_gemm(acc, As, wf, m, g, l);
    float bia[8];
    #pragma unroll
    for (int nt = 0; nt < 8; ++nt) bia[nt] = ba1[nt * 16 + lo16];
    #pragma unroll
    for (int nt = 0; nt < 8; ++nt)
        #pragma unroll
        for (int i = 0; i < 4; ++i) acc[nt][i] += bia[nt];

    float mu_[4], rs_[4];
    #pragma unroll
    for (int i = 0; i < 4; ++i) {
        float sm = 0.f;
        #pragma unroll
        for (int nt = 0; nt < 8; ++nt) sm += acc[nt][i];
        #pragma unroll
        for (int k = 1; k < 16; k <<= 1) sm += __shfl_xor(sm, k, 16);
        mu_[i] = sm * (1.f / 128.f);
        float vs = 0.f;
        #pragma unroll
        for (int nt = 0; nt < 8; ++nt) { float d = acc[nt][i] - mu_[i]; vs += d * d; }
        #pragma unroll
        for (int k = 1; k < 16; k <<= 1) vs += __shfl_xor(vs, k, 16);
        rs_[i] = rsqrtf(vs * (1.f / 128.f) + 1e-5f);
    }
    float gam[8], bet[8];
    #pragma unroll
    for (int nt = 0; nt < 8; ++nt) { gam[nt] = ln_g[nt * 16 + lo16]; bet[nt] = ln_b[nt * 16 + lo16]; }

    __syncthreads();
    #pragma unroll
    for (int nt = 0; nt < 8; ++nt)
        #pragma unroll
        for (int i = 0; i < 4; ++i) {
            float h = fmaf((acc[nt][i] - mu_[i]) * rs_[i], gam[nt], bet[nt]);
            As[wv * 16 + g * 4 + i][nt * 16 + lo16] = packhl(fmaxf(h, 0.f));
        }
    __syncthreads();

    mlp_gemm(acc, As, wf + 32 * 64 * 8, m, g, l);
    #pragma unroll
    for (int nt = 0; nt < 8; ++nt) bia[nt] = ba2[nt * 16 + lo16];
    __syncthreads();
    #pragma unroll
    for (int nt = 0; nt < 8; ++nt)
        #pragma unroll
        for (int i = 0; i < 4; ++i)
            As[wv * 16 + g * 4 + i][nt * 16 + lo16] = packhl(acc[nt][i] + bia[nt]);
    __syncthreads();

    mlp_gemm(acc, As, wf + 2 * 32 * 64 * 8, m, g, l);
    #pragma unroll
    for (int nt = 0; nt < 8; ++nt) bia[nt] = bd[nt * 16 + lo16];
    #pragma unroll
    for (int i = 0; i < 4; ++i) {
        int row = c0 + wv * 16 + g * 4 + i;
        if (row < nC) {
            float* dst = cm + ((size_t)b * TT + row) * DD + lo16;
            #pragma unroll
            for (int nt = 0; nt < 8; ++nt) {
                float z = acc[nt][i] + bia[nt];
                dst[nt * 16] = 1.f / (1.f + __expf(-z));
            }
        }
    }
}

// ---------------------------------------------------------------------------
// Kernel 4: out[t] = fma(x[t], gate[seg[t]], x[t])  (unchanged)
// ---------------------------------------------------------------------------
__global__ __launch_bounds__(256) void k_out(const float* __restrict__ x,
    const int* __restrict__ seg, const float* __restrict__ gate, float* __restrict__ out)
{
    const size_t idx = (size_t)blockIdx.x * 256 + threadIdx.x;
    const size_t tok = idx >> 5;
    const int d4 = (int)(idx & 31);
    const int b  = (int)(tok >> 14);
    const int sg = seg[tok];
    float4 gv = ld4(gate + (((size_t)b << 14) + sg) * DD + d4 * 4);
    float4 xv = ld4(x + tok * DD + (size_t)d4 * 4);
    float4 o;
    o.x = fmaf(xv.x, gv.x, xv.x);
    o.y = fmaf(xv.y, gv.y, xv.y);
    o.z = fmaf(xv.z, gv.z, xv.z);
    o.w = fmaf(xv.w, gv.w, xv.w);
    *(float4*)(out + idx * 4) = o;
}

extern "C" void kernel_launch(void* const* d_in, const int* in_sizes, int n_in,
                              void* d_out, int out_size, void* d_ws, size_t ws_size,
                              hipStream_t stream)
{
    (void)in_sizes; (void)n_in; (void)out_size; (void)ws_size;
    const float* x    = (const float*)d_in[0];
    const float* Wk   = (const float*)d_in[1];
    const float* bk   = (const float*)d_in[2];
    const float* Wq   = (const float*)d_in[3];
    const float* bq   = (const float*)d_in[4];
    const float* Wa1  = (const float*)d_in[5];
    const float* ba1  = (const float*)d_in[6];
    const float* ln_g = (const float*)d_in[7];
    const float* ln_b = (const float*)d_in[8];
    const float* Wa2  = (const float*)d_in[9];
    const float* ba2  = (const float*)d_in[10];
    const float* Wd   = (const float*)d_in[11];
    const float* bd   = (const float*)d_in[12];
    float* out = (float*)d_out;

    // ws layout
    char* p = (char*)d_ws;
    float* cm   = (float*)p;   p += (size_t)BB * TT * DD * 4;   // 64 MB (reused as gate)
    int* seg    = (int*)p;     p += (size_t)BB * TT * 4;        // bind bits, then seg ids
    int* cs     = (int*)p;     p += (size_t)BB * (TT + 1) * 4;
    int* numC   = (int*)p;     p += 64;
    ushort* wfm = (ushort*)p;  p += 3 * DD * DD * 2;            // MLP W frags (96 KB)
    ushort* wfb = (ushort*)p;  p += 2 * DD * DD * 2;            // bind W frags hi+lo (64 KB)
    int* flist  = (int*)p;     p += (size_t)FCAP * 4;           // fixup list (128 KB)
    int* fcnt   = (int*)p;

    k_wprep<<<dim3(32, 4), 64, 0, stream>>>(Wa1, Wa2, Wd, Wk, Wq, wfm, wfb, fcnt);
    k_bind<<<dim3(256, BB), 256, 0, stream>>>(x, wfb, bk, bq, seg, flist, fcnt);
    k_fixup<<<dim3(256), 256, 0, stream>>>(x, Wk, bk, Wq, bq, flist, fcnt, seg);
    k_scan<<<dim3(BB), 1024, 0, stream>>>(seg, seg, cs, numC);
    k_mean<<<dim3(BB * TT / 4), 256, 0, stream>>>(x, cs, numC, cm);
    k_mlp<<<dim3(TT / 64, BB), 256, 0, stream>>>(ba1, ln_g, ln_b, ba2, bd, wfm, numC, cm);
    k_out<<<dim3(BB * TT * DD / (256 * 4)), 256, 0, stream>>>(x, seg, cm, out);
}

// Round 6
// 143.892 us; speedup vs baseline: 1.0239x; 1.0239x over previous
//
#include <hip/hip_runtime.h>
#include <math.h>

#define BB 8
#define TT 16384
#define DD 128
#define DH 64
#define FCAP 32768
#define FMARGIN 0.02f

typedef short short8 __attribute__((ext_vector_type(8)));
typedef float f32x4  __attribute__((ext_vector_type(4)));

static __device__ __forceinline__ float4 ld4(const float* p) { return *(const float4*)p; }

// bf16 round-to-nearest-even
static __device__ __forceinline__ uint f2bf(float x) {
    uint u = __float_as_uint(x);
    return (u + 0x7FFFu + ((u >> 16) & 1u)) >> 16;
}
// pack value x ~= hi + lo (both bf16) into u32 = (hi<<16)|lo
static __device__ __forceinline__ uint packhl(float x) {
    uint hb = f2bf(x);
    float hf = __uint_as_float(hb << 16);
    uint lb = f2bf(x - hf);
    return (hb << 16) | lb;
}

// split 8 fp32 -> hi bf16x8 + lo bf16x8 (in-register)
static __device__ __forceinline__ void split8(const float4 v0, const float4 v1,
                                              short8* ah, short8* al)
{
    float f[8] = {v0.x, v0.y, v0.z, v0.w, v1.x, v1.y, v1.z, v1.w};
    union { uint u[4]; short8 s; } H, L;
    #pragma unroll
    for (int j = 0; j < 4; ++j) {
        uint h0 = f2bf(f[2 * j]);
        uint h1 = f2bf(f[2 * j + 1]);
        uint l0 = f2bf(f[2 * j]     - __uint_as_float(h0 << 16));
        uint l1 = f2bf(f[2 * j + 1] - __uint_as_float(h1 << 16));
        H.u[j] = h0 | (h1 << 16);
        L.u[j] = l0 | (l1 << 16);
    }
    *ah = H.s; *al = L.s;
}

// ---------------------------------------------------------------------------
// Kernel W-prep: weights fp32 -> bf16 MFMA B-fragment layout.
// ly 0..2: MLP layers Wa1/Wa2/Wd -> wfm (hi only). ly 3: bind [Wk|Wq] -> wfb
// hi frags [0, D*D) and lo frags [D*D, 2*D*D). Zeroes the fixup counter.
// ---------------------------------------------------------------------------
__global__ __launch_bounds__(64) void k_wprep(
    const float* __restrict__ Wa1, const float* __restrict__ Wa2,
    const float* __restrict__ Wd, const float* __restrict__ Wk,
    const float* __restrict__ Wq, ushort* __restrict__ wfm,
    ushort* __restrict__ wfb, int* __restrict__ fcnt)
{
    const int l  = threadIdx.x;
    const int nt = blockIdx.x & 7;
    const int kb = blockIdx.x >> 3;
    const int ly = blockIdx.y;
    if (ly == 0 && blockIdx.x == 0 && l == 0) *fcnt = 0;
    const int n  = nt * 16 + (l & 15);
    const int k0 = kb * 32 + (l >> 4) * 8;
    if (ly < 3) {
        const float* W = (ly == 0) ? Wa1 : (ly == 1) ? Wa2 : Wd;
        short8 v;
        #pragma unroll
        for (int e = 0; e < 8; ++e) v[e] = (short)(ushort)f2bf(W[(k0 + e) * DD + n]);
        *(short8*)(wfm + (size_t)(((ly * 8 + nt) * 4 + kb) * 64 + l) * 8) = v;
    } else {
        short8 vh, vl;
        #pragma unroll
        for (int e = 0; e < 8; ++e) {
            float w = (n < 64) ? Wk[(k0 + e) * DH + n] : Wq[(k0 + e) * DH + n - 64];
            uint hb = f2bf(w);
            vh[e] = (short)(ushort)hb;
            vl[e] = (short)(ushort)f2bf(w - __uint_as_float(hb << 16));
        }
        *(short8*)(wfb + (size_t)((nt * 4 + kb) * 64 + l) * 8) = vh;
        *(short8*)(wfb + (size_t)DD * DD + (size_t)((nt * 4 + kb) * 64 + l) * 8) = vl;
    }
}

// ---------------------------------------------------------------------------
// Kernel 1: binding logits via MFMA, 3-product split (ah*wh + al*wh + ah*wl).
// Restructured for load ILP: all x A-frags split up front; per kb the FULL
// bh[8]/bl[8] B-frag set is loaded into registers BEFORE the 24-MFMA group
// (forces wide vmcnt pipelining; round-5's 56-VGPR version serialized loads).
// __launch_bounds__(256,2): allow up to 256 VGPRs.
// ---------------------------------------------------------------------------
__global__ __launch_bounds__(256, 2) void k_bind(
    const float* __restrict__ x, const ushort* __restrict__ wfb,
    const float* __restrict__ bk, const float* __restrict__ bq,
    int* __restrict__ cstart, int* __restrict__ flist, int* __restrict__ fcnt)
{
    __shared__ struct { float K[64][66]; float Q[65][66]; } kq;   // 34.1 KB
    const int b    = blockIdx.y;
    const int tb   = blockIdx.x * 64;
    const int tid  = threadIdx.x;
    const int wv   = tid >> 6;
    const int l    = tid & 63;
    const int lo16 = l & 15;
    const int g    = l >> 4;

    // ---- load + split all main-tile A-frags (8 loads, issued together) ----
    const float* xrow = x + ((size_t)b * TT + tb + wv * 16 + lo16) * DD;
    short8 ah[4], al[4];
    #pragma unroll
    for (int kb = 0; kb < 4; ++kb) {
        float4 v0 = ld4(xrow + kb * 32 + g * 8);
        float4 v1 = ld4(xrow + kb * 32 + g * 8 + 4);
        split8(v0, v1, &ah[kb], &al[kb]);
    }
    // issue Q-row-64 loads early (only lo16==0 lanes carry real data)
    int r64 = tb + 64; if (r64 > TT - 1) r64 = TT - 1;   // clamp; value unused when t>TT-2
    const float* xq = x + ((size_t)b * TT + r64) * DD;
    float4 q0[4], q1[4];
    #pragma unroll
    for (int kb = 0; kb < 4; ++kb) {
        q0[kb] = make_float4(0.f, 0.f, 0.f, 0.f);
        q1[kb] = make_float4(0.f, 0.f, 0.f, 0.f);
        if (lo16 == 0) { q0[kb] = ld4(xq + kb * 32 + g * 8); q1[kb] = ld4(xq + kb * 32 + g * 8 + 4); }
    }

    // ---- main m-tile: rows wv*16..+15, n-tiles 0..7 (K | Q) ----
    f32x4 acc[8];
    #pragma unroll
    for (int nt = 0; nt < 8; ++nt) {
        int col = nt * 16 + lo16;
        float bias = (col < 64) ? bk[col] : bq[col - 64];
        acc[nt] = (f32x4){bias, bias, bias, bias};
    }
    #pragma unroll
    for (int kb = 0; kb < 4; ++kb) {
        short8 bh[8], bl[8];
        #pragma unroll
        for (int nt = 0; nt < 8; ++nt) {
            bh[nt] = *(const short8*)(wfb + (size_t)((nt * 4 + kb) * 64 + l) * 8);
            bl[nt] = *(const short8*)(wfb + (size_t)DD * DD + (size_t)((nt * 4 + kb) * 64 + l) * 8);
        }
        #pragma unroll
        for (int nt = 0; nt < 8; ++nt) {
            acc[nt] = __builtin_amdgcn_mfma_f32_16x16x32_bf16(ah[kb], bh[nt], acc[nt], 0, 0, 0);
            acc[nt] = __builtin_amdgcn_mfma_f32_16x16x32_bf16(al[kb], bh[nt], acc[nt], 0, 0, 0);
            acc[nt] = __builtin_amdgcn_mfma_f32_16x16x32_bf16(ah[kb], bl[nt], acc[nt], 0, 0, 0);
        }
    }

    // ---- tile 4: Q row 64 only (A rows 1..15 zero), n-tile 4+wv ----
    f32x4 acc4;
    {
        int col = (4 + wv) * 16 + lo16;
        float bias = bq[col - 64];
        acc4 = (f32x4){bias, bias, bias, bias};
    }
    #pragma unroll
    for (int kb = 0; kb < 4; ++kb) {
        short8 qh, ql;
        split8(q0[kb], q1[kb], &qh, &ql);
        short8 bh = *(const short8*)(wfb + (size_t)(((4 + wv) * 4 + kb) * 64 + l) * 8);
        short8 bl = *(const short8*)(wfb + (size_t)DD * DD + (size_t)(((4 + wv) * 4 + kb) * 64 + l) * 8);
        acc4 = __builtin_amdgcn_mfma_f32_16x16x32_bf16(qh, bh, acc4, 0, 0, 0);
        acc4 = __builtin_amdgcn_mfma_f32_16x16x32_bf16(ql, bh, acc4, 0, 0, 0);
        acc4 = __builtin_amdgcn_mfma_f32_16x16x32_bf16(qh, bl, acc4, 0, 0, 0);
    }

    // C/D layout: col = lane&15 (+nt*16), row = (lane>>4)*4 + reg
    #pragma unroll
    for (int nt = 0; nt < 8; ++nt)
        #pragma unroll
        for (int i = 0; i < 4; ++i) {
            int row = wv * 16 + g * 4 + i;
            int col = nt * 16 + lo16;
            if (nt < 4) kq.K[row][col]      = acc[nt][i];
            else        kq.Q[row][col - 64] = acc[nt][i];
        }
    if (g == 0) kq.Q[64][wv * 16 + lo16] = acc4[0];   // row 64 = reg 0 of g==0
    __syncthreads();

    // dot: 4 threads per bind index, 16 elems each
    const int tr = tid >> 2, part = tid & 3;
    float s = 0.f;
    #pragma unroll
    for (int j4 = 0; j4 < 4; ++j4) {
        float4 kv = *(const float4*)&kq.K[tr][part * 16 + j4 * 4];
        float4 qv = *(const float4*)&kq.Q[tr + 1][part * 16 + j4 * 4];
        s += kv.x * qv.x + kv.y * qv.y + kv.z * qv.z + kv.w * qv.w;
    }
    s += __shfl_xor(s, 1);
    s += __shfl_xor(s, 2);
    if (part == 0) {
        int t = tb + tr;
        if (t <= TT - 2) {
            cstart[b * TT + t + 1] = (s > 0.f) ? 0 : 1;
            if (fabsf(s) < FMARGIN) {
                int pos = atomicAdd(fcnt, 1);
                if (pos < FCAP) flist[pos] = b * TT + t;
            }
        }
    }
    if (blockIdx.x == 0 && tid == 0) cstart[b * TT] = 1;
}

// ---------------------------------------------------------------------------
// Kernel 1b: exact fp32 recompute of flagged borderline bind decisions.
// ---------------------------------------------------------------------------
__global__ __launch_bounds__(256) void k_fixup(
    const float* __restrict__ x, const float* __restrict__ Wk, const float* __restrict__ bk,
    const float* __restrict__ Wq, const float* __restrict__ bq,
    const int* __restrict__ flist, const int* __restrict__ fcnt, int* __restrict__ cstart)
{
    const int n    = min(*fcnt, FCAP);
    const int wv   = (blockIdx.x * 256 + threadIdx.x) >> 6;
    const int lane = threadIdx.x & 63;
    const int nwv  = gridDim.x * 4;
    for (int i = wv; i < n; i += nwv) {
        int idx = flist[i];
        int b = idx >> 14;
        int t = idx & (TT - 1);
        const float* xt = x + ((size_t)b * TT + t) * DD;
        float K = bk[lane], Q = bq[lane];
        #pragma unroll 8
        for (int k = 0; k < DD; ++k) {
            K = fmaf(xt[k],      Wk[k * DH + lane], K);
            Q = fmaf(xt[DD + k], Wq[k * DH + lane], Q);
        }
        float p = K * Q;
        #pragma unroll
        for (int m = 1; m < 64; m <<= 1) p += __shfl_xor(p, m);
        if (lane == 0) cstart[b * TT + t + 1] = (p > 0.f) ? 0 : 1;
    }
}

// ---------------------------------------------------------------------------
// Kernel 2: per-batch scan -> seg, chunk-start table, counts.
// Wave-shfl scan (6 steps) + 16-wavesum scan: 2 barriers total (was 20).
// ---------------------------------------------------------------------------
__global__ __launch_bounds__(1024) void k_scan(const int* __restrict__ cstart,
    int* __restrict__ seg, int* __restrict__ cs, int* __restrict__ numC)
{
    __shared__ int wsum[16];
    const int b = blockIdx.x, tid = threadIdx.x;
    const int wv = tid >> 6, lane = tid & 63;
    const int base = b * TT + tid * 16;
    int v[16];
    #pragma unroll
    for (int i = 0; i < 4; ++i) {
        int4 q = *(const int4*)(cstart + base + i * 4);
        v[i * 4 + 0] = q.x; v[i * 4 + 1] = q.y; v[i * 4 + 2] = q.z; v[i * 4 + 3] = q.w;
    }
    int s[16]; int run = 0;
    #pragma unroll
    for (int i = 0; i < 16; ++i) { run += v[i]; s[i] = run; }
    // wave-level inclusive scan of per-thread totals
    int incl = run;
    #pragma unroll
    for (int off = 1; off < 64; off <<= 1) {
        int t = __shfl_up(incl, off);
        if (lane >= off) incl += t;
    }
    if (lane == 63) wsum[wv] = incl;
    __syncthreads();
    if (tid < 16) {
        int w = wsum[tid];
        #pragma unroll
        for (int off = 1; off < 16; off <<= 1) {
            int t = __shfl_up(w, off, 16);
            if (tid >= off) w += t;
        }
        wsum[tid] = w;
    }
    __syncthreads();
    const int excl = (wv ? wsum[wv - 1] : 0) + incl - run;
    #pragma unroll
    for (int i = 0; i < 16; ++i) {
        int sg = excl + s[i] - 1;
        seg[base + i] = sg;
        if (v[i]) cs[b * (TT + 1) + sg] = tid * 16 + i;
    }
    if (tid == 1023) {
        int tot = excl + run;
        numC[b] = tot;
        cs[b * (TT + 1) + tot] = TT;
    }
}

// ---------------------------------------------------------------------------
// k_mlp GEMM helper: acc[8] (16x128 per wave) = A(split hi+lo) @ W_bf16.
// ---------------------------------------------------------------------------
__device__ __forceinline__ void mlp_gemm(f32x4 acc[8], const uint (*As)[132],
    const ushort* __restrict__ wl, int m, int g, int l)
{
    #pragma unroll
    for (int nt = 0; nt < 8; ++nt) acc[nt] = (f32x4){0.f, 0.f, 0.f, 0.f};
    #pragma unroll
    for (int kb = 0; kb < 4; ++kb) {
        short8 bh[8];
        #pragma unroll
        for (int nt = 0; nt < 8; ++nt)
            bh[nt] = *(const short8*)(wl + (size_t)((nt * 4 + kb) * 64 + l) * 8);
        uint4 p0 = *(const uint4*)&As[m][kb * 32 + g * 8];
        uint4 p1 = *(const uint4*)&As[m][kb * 32 + g * 8 + 4];
        uint pp[8] = {p0.x, p0.y, p0.z, p0.w, p1.x, p1.y, p1.z, p1.w};
        union { uint u[4]; short8 s; } ah, al;
        #pragma unroll
        for (int j = 0; j < 4; ++j) {
            ah.u[j] = (pp[2 * j] >> 16)      | (pp[2 * j + 1] & 0xFFFF0000u);
            al.u[j] = (pp[2 * j] & 0xFFFFu)  | (pp[2 * j + 1] << 16);
        }
        #pragma unroll
        for (int nt = 0; nt < 8; ++nt) {
            acc[nt] = __builtin_amdgcn_mfma_f32_16x16x32_bf16(ah.s, bh[nt], acc[nt], 0, 0, 0);
            acc[nt] = __builtin_amdgcn_mfma_f32_16x16x32_bf16(al.s, bh[nt], acc[nt], 0, 0, 0);
        }
    }
}

// ---------------------------------------------------------------------------
// Kernel 3: per-chunk MLP via MFMA, with FUSED chunk-mean staging (k_mean
// deleted): each staging thread sums its 4 dims over the chunk's contiguous
// token range (same fp32 order as old k_mean -> bit-identical), divides,
// packs hi|lo bf16 into LDS. Gate written to cm.
// ---------------------------------------------------------------------------
__global__ __launch_bounds__(256) void k_mlp(
    const float* __restrict__ x, const int* __restrict__ cs,
    const float* __restrict__ ba1, const float* __restrict__ ln_g, const float* __restrict__ ln_b,
    const float* __restrict__ ba2, const float* __restrict__ bd,
    const ushort* __restrict__ wf, const int* __restrict__ numC, float* __restrict__ cm)
{
    __shared__ uint As[64][132];
    const int b  = blockIdx.y;
    const int nC = numC[b];
    const int c0 = blockIdx.x * 64;
    if (c0 >= nC) return;
    const int tid  = threadIdx.x;
    const int wv   = tid >> 6;
    const int l    = tid & 63;
    const int lo16 = l & 15;
    const int g    = l >> 4;
    const int m    = wv * 16 + lo16;

    // fused mean staging: thread covers chunk row r = i>>5, dims c4..c4+3
    for (int i = tid; i < 64 * 32; i += 256) {
        int r = i >> 5, c4 = (i & 31) * 4;
        float4 sv = make_float4(0.f, 0.f, 0.f, 0.f);
        int c = c0 + r;
        if (c < nC) {
            int t0 = cs[b * (TT + 1) + c], t1 = cs[b * (TT + 1) + c + 1];
            const float* xp = x + ((size_t)b * TT + t0) * DD + c4;
            for (int t = t0; t < t1; ++t, xp += DD) {
                float4 v = ld4(xp);
                sv.x += v.x; sv.y += v.y; sv.z += v.z; sv.w += v.w;
            }
            float inv = 1.f / (float)(t1 - t0);
            sv.x *= inv; sv.y *= inv; sv.z *= inv; sv.w *= inv;
        }
        uint4 pk;
        pk.x = packhl(sv.x); pk.y = packhl(sv.y); pk.z = packhl(sv.z); pk.w = packhl(sv.w);
        *(uint4*)&As[r][c4] = pk;
    }
    __syncthreads();

    f32x4 acc[8];
    mlp_gemm(acc, As, wf, m, g, l);
    float bia[8];
    #pragma unroll
    for (int nt = 0; nt < 8; ++nt) bia[nt] = ba1[nt * 16 + lo16];
    #pragma unroll
    for (int nt = 0; nt < 8; ++nt)
        #pragma unroll
        for (int i = 0; i < 4; ++i) acc[nt][i] += bia[nt];

    float mu_[4], rs_[4];
    #pragma unroll
    for (int i = 0; i < 4; ++i) {
        float sm = 0.f;
        #pragma unroll
        for (int nt = 0; nt < 8; ++nt) sm += acc[nt][i];
        #pragma unroll
        for (int k = 1; k < 16; k <<= 1) sm += __shfl_xor(sm, k, 16);
        mu_[i] = sm * (1.f / 128.f);
        float vs = 0.f;
        #pragma unroll
        for (int nt = 0; nt < 8; ++nt) { float d = acc[nt][i] - mu_[i]; vs += d * d; }
        #pragma unroll
        for (int k = 1; k < 16; k <<= 1) vs += __shfl_xor(vs, k, 16);
        rs_[i] = rsqrtf(vs * (1.f / 128.f) + 1e-5f);
    }
    float gam[8], bet[8];
    #pragma unroll
    for (int nt = 0; nt < 8; ++nt) { gam[nt] = ln_g[nt * 16 + lo16]; bet[nt] = ln_b[nt * 16 + lo16]; }

    __syncthreads();
    #pragma unroll
    for (int nt = 0; nt < 8; ++nt)
        #pragma unroll
        for (int i = 0; i < 4; ++i) {
            float h = fmaf((acc[nt][i] - mu_[i]) * rs_[i], gam[nt], bet[nt]);
            As[wv * 16 + g * 4 + i][nt * 16 + lo16] = packhl(fmaxf(h, 0.f));
        }
    __syncthreads();

    mlp_gemm(acc, As, wf + 32 * 64 * 8, m, g, l);
    #pragma unroll
    for (int nt = 0; nt < 8; ++nt) bia[nt] = ba2[nt * 16 + lo16];
    __syncthreads();
    #pragma unroll
    for (int nt = 0; nt < 8; ++nt)
        #pragma unroll
        for (int i = 0; i < 4; ++i)
            As[wv * 16 + g * 4 + i][nt * 16 + lo16] = packhl(acc[nt][i] + bia[nt]);
    __syncthreads();

    mlp_gemm(acc, As, wf + 2 * 32 * 64 * 8, m, g, l);
    #pragma unroll
    for (int nt = 0; nt < 8; ++nt) bia[nt] = bd[nt * 16 + lo16];
    #pragma unroll
    for (int i = 0; i < 4; ++i) {
        int row = c0 + wv * 16 + g * 4 + i;
        if (row < nC) {
            float* dst = cm + ((size_t)b * TT + row) * DD + lo16;
            #pragma unroll
            for (int nt = 0; nt < 8; ++nt) {
                float z = acc[nt][i] + bia[nt];
                dst[nt * 16] = 1.f / (1.f + __expf(-z));
            }
        }
    }
}

// ---------------------------------------------------------------------------
// Kernel 4: out[t] = fma(x[t], gate[seg[t]], x[t])  (unchanged)
// ---------------------------------------------------------------------------
__global__ __launch_bounds__(256) void k_out(const float* __restrict__ x,
    const int* __restrict__ seg, const float* __restrict__ gate, float* __restrict__ out)
{
    const size_t idx = (size_t)blockIdx.x * 256 + threadIdx.x;
    const size_t tok = idx >> 5;
    const int d4 = (int)(idx & 31);
    const int b  = (int)(tok >> 14);
    const int sg = seg[tok];
    float4 gv = ld4(gate + (((size_t)b << 14) + sg) * DD + d4 * 4);
    float4 xv = ld4(x + tok * DD + (size_t)d4 * 4);
    float4 o;
    o.x = fmaf(xv.x, gv.x, xv.x);
    o.y = fmaf(xv.y, gv.y, xv.y);
    o.z = fmaf(xv.z, gv.z, xv.z);
    o.w = fmaf(xv.w, gv.w, xv.w);
    *(float4*)(out + idx * 4) = o;
}

extern "C" void kernel_launch(void* const* d_in, const int* in_sizes, int n_in,
                              void* d_out, int out_size, void* d_ws, size_t ws_size,
                              hipStream_t stream)
{
    (void)in_sizes; (void)n_in; (void)out_size; (void)ws_size;
    const float* x    = (const float*)d_in[0];
    const float* Wk   = (const float*)d_in[1];
    const float* bk   = (const float*)d_in[2];
    const float* Wq   = (const float*)d_in[3];
    const float* bq   = (const float*)d_in[4];
    const float* Wa1  = (const float*)d_in[5];
    const float* ba1  = (const float*)d_in[6];
    const float* ln_g = (const float*)d_in[7];
    const float* ln_b = (const float*)d_in[8];
    const float* Wa2  = (const float*)d_in[9];
    const float* ba2  = (const float*)d_in[10];
    const float* Wd   = (const float*)d_in[11];
    const float* bd   = (const float*)d_in[12];
    float* out = (float*)d_out;

    // ws layout
    char* p = (char*)d_ws;
    float* cm   = (float*)p;   p += (size_t)BB * TT * DD * 4;   // 64 MB (gate)
    int* seg    = (int*)p;     p += (size_t)BB * TT * 4;        // bind bits, then seg ids
    int* cs     = (int*)p;     p += (size_t)BB * (TT + 1) * 4;
    int* numC   = (int*)p;     p += 64;
    ushort* wfm = (ushort*)p;  p += 3 * DD * DD * 2;            // MLP W frags (96 KB)
    ushort* wfb = (ushort*)p;  p += 2 * DD * DD * 2;            // bind W frags hi+lo (64 KB)
    int* flist  = (int*)p;     p += (size_t)FCAP * 4;           // fixup list (128 KB)
    int* fcnt   = (int*)p;

    k_wprep<<<dim3(32, 4), 64, 0, stream>>>(Wa1, Wa2, Wd, Wk, Wq, wfm, wfb, fcnt);
    k_bind<<<dim3(256, BB), 256, 0, stream>>>(x, wfb, bk, bq, seg, flist, fcnt);
    k_fixup<<<dim3(256), 256, 0, stream>>>(x, Wk, bk, Wq, bq, flist, fcnt, seg);
    k_scan<<<dim3(BB), 1024, 0, stream>>>(seg, seg, cs, numC);
    k_mlp<<<dim3(TT / 64, BB), 256, 0, stream>>>(x, cs, ba1, ln_g, ln_b, ba2, bd, wfm, numC, cm);
    k_out<<<dim3(BB * TT * DD / (256 * 4)), 256, 0, stream>>>(x, seg, cm, out);
}